// Round 3
// baseline (749.033 us; speedup 1.0000x reference)
//
#include <hip/hip_runtime.h>
#include <hip/hip_bf16.h>
#include <stdint.h>

// ---------------------------------------------------------------------------
// MoE top-2 with capacity, per-expert RMSNorm + SwiGLU FFN.  fp32 I/O,
// bf16 MFMA internals.  N=16384, D=768, E=8, H=2048, CAP=5120.
// Round 8: gemm1/gemm2 ported to a 256x256 / 512-thread / deep-pipeline
// schedule (T3+T4+T5):
//   - BK=32, FOUR LDS K-tile buffers (128 KiB), prefetch distance 3:
//     iter tk stages tile tk+3 into buf[(tk+3)&3] (WAR-safe: that buffer
//     was last read at tk-1, before the last barrier), computes buf[tk&3],
//     then waits vmcnt(8) (counted -- tiles tk+2/tk+3 stay in flight
//     across the barrier) + ONE raw s_barrier per K-tile.
//   - 64B-row swizzle both-sides: LDS slot s holds global slot
//     s ^ ((row>>1)&3); inverse folded into per-lane global_load_lds src.
//   - s_setprio(1) around MFMA clusters, sched_barrier(0) pins.
//   - gemm1 keeps g/u SwiGLU pairing in-register (B tile = 128 g + 128 u
//     rows, wave wc owns cols wc*32 of both) -> silu from f32 acc.
// Carried: global_load_lds(16B), XCD chunk swizzle, LDS-round-trip
// coalesced epilogues, LDS-staged dispatch.
// ---------------------------------------------------------------------------

#define N_TOK 16384
#define D_    768
#define E_    8
#define H_    2048
#define CAP   5120
#define NK    (N_TOK * 2)
#define EPS_  1e-6f

typedef unsigned short u16;
typedef unsigned char  u8;
typedef __attribute__((ext_vector_type(8))) __bf16 v8bf;
typedef __attribute__((ext_vector_type(4))) float  v4f;

typedef __attribute__((address_space(3))) unsigned int lds_u32;
typedef const __attribute__((address_space(1))) unsigned int glb_u32;

__device__ __forceinline__ void gload16(const void* g, void* lds) {
    __builtin_amdgcn_global_load_lds((glb_u32*)g, (lds_u32*)lds, 16, 0, 0);
}

__device__ __forceinline__ float bf2f(u16 u) {
    union { uint32_t i; float f; } v; v.i = ((uint32_t)u) << 16; return v.f;
}
__device__ __forceinline__ u16 f2bf(float f) {
    union { uint32_t i; float f; } v; v.f = f;
    uint32_t r = v.i + 0x7fffu + ((v.i >> 16) & 1u);
    return (u16)(r >> 16);
}

// ---------------------------------------------------------------------------
// fp32 -> bf16 weight conversion, float4 granularity, grid-stride.
// ---------------------------------------------------------------------------
__global__ __launch_bounds__(256) void conv_bf16_kernel(
    const float* __restrict__ src, u16* __restrict__ dst, int n4)
{
    for (int i = blockIdx.x * 256 + threadIdx.x; i < n4; i += gridDim.x * 256) {
        float4 v = ((const float4*)src)[i];
        ushort4 o;
        o.x = f2bf(v.x); o.y = f2bf(v.y); o.z = f2bf(v.z); o.w = f2bf(v.w);
        ((ushort4*)dst)[i] = o;
    }
}

// ---------------------------------------------------------------------------
// Router: one wave per token; top-2; w0 = 1/(1+exp(l1-l0)).
// ---------------------------------------------------------------------------
__global__ __launch_bounds__(256) void router_kernel(
    const float* __restrict__ x, const float* __restrict__ gate_w,
    int* __restrict__ routerEx, float* __restrict__ routerW)
{
    __shared__ float gw[E_ * D_];
    int t = threadIdx.x;
    for (int i = t; i < E_ * D_; i += 256) gw[i] = gate_w[i];
    __syncthreads();
    int wv = t >> 6, l = t & 63;
    int n = blockIdx.x * 4 + wv;
    const float* xr = x + (size_t)n * D_;
    float p[E_];
#pragma unroll
    for (int e = 0; e < E_; ++e) p[e] = 0.f;
#pragma unroll
    for (int j = 0; j < 12; ++j) {
        int d = l + 64 * j;
        float xv = xr[d];
#pragma unroll
        for (int e = 0; e < E_; ++e) p[e] += xv * gw[e * D_ + d];
    }
#pragma unroll
    for (int off = 32; off > 0; off >>= 1) {
#pragma unroll
        for (int e = 0; e < E_; ++e) p[e] += __shfl_xor(p[e], off, 64);
    }
    if (l == 0) {
        int e0 = 0; float m0 = p[0];
#pragma unroll
        for (int e = 1; e < E_; ++e) if (p[e] > m0) { m0 = p[e]; e0 = e; }
        int e1 = (e0 == 0) ? 1 : 0; float m1 = p[e1];
#pragma unroll
        for (int e = 0; e < E_; ++e) if (e != e0 && p[e] > m1) { m1 = p[e]; e1 = e; }
        float w0 = 1.f / (1.f + __expf(m1 - m0));
        routerEx[2 * n] = e0; routerEx[2 * n + 1] = e1;
        routerW[2 * n] = w0; routerW[2 * n + 1] = 1.f - w0;
    }
}

// ---------------------------------------------------------------------------
// Dispatch: exact token-major (i = n*2+k) capacity ranking, single block.
// ---------------------------------------------------------------------------
__global__ __launch_bounds__(256) void dispatch_kernel(
    const int* __restrict__ routerEx, int* __restrict__ tokenSlot,
    int* __restrict__ slotToken, int* __restrict__ cnt)
{
    __shared__ u8  exs[NK + NK / 128];   // 33 KB
    __shared__ int hist[256 * E_];       // 8 KB
    int t = threadIdx.x;
    for (int i = t; i < NK; i += 256)
        exs[i + (i >> 7)] = (u8)routerEx[i];
    __syncthreads();
    int loc[E_];
#pragma unroll
    for (int e = 0; e < E_; ++e) loc[e] = 0;
    int abase = t * 129;                 // t*128 + pad(t)
    for (int j = 0; j < NK / 256; ++j) {
        int ev = exs[abase + j];
#pragma unroll
        for (int e = 0; e < E_; ++e) loc[e] += (ev == e) ? 1 : 0;
    }
#pragma unroll
    for (int e = 0; e < E_; ++e) hist[t * E_ + e] = loc[e];
    __syncthreads();
    if (t < E_) {
        int run = 0;
        for (int tt = 0; tt < 256; ++tt) { int v = hist[tt * E_ + t]; hist[tt * E_ + t] = run; run += v; }
        cnt[t] = run;
    }
    __syncthreads();
    int off[E_];
#pragma unroll
    for (int e = 0; e < E_; ++e) off[e] = hist[t * E_ + e];
    int base = t * (NK / 256);
    for (int j = 0; j < NK / 256; ++j) {
        int i = base + j;
        int ev = exs[abase + j];
        int pos = 0;
#pragma unroll
        for (int e = 0; e < E_; ++e) { if (ev == e) { pos = off[e]; off[e] = pos + 1; } }
        if (pos < CAP) {
            int s = ev * CAP + pos;
            tokenSlot[i] = s;
            slotToken[s] = i;
        } else {
            tokenSlot[i] = -1;
        }
    }
}

// ---------------------------------------------------------------------------
// init_out: out[n] = (sum kept w) * x[n]   (per-expert path only)
// ---------------------------------------------------------------------------
__global__ __launch_bounds__(256) void init_out_kernel(
    const float* __restrict__ x, const int* __restrict__ tokenSlot,
    const float* __restrict__ routerW, float* __restrict__ out)
{
    int g = blockIdx.x * 256 + threadIdx.x;
    int n = g / 96;
    int d0 = (g - n * 96) * 8;
    float w0 = (tokenSlot[2 * n] >= 0) ? routerW[2 * n] : 0.f;
    float w1 = (tokenSlot[2 * n + 1] >= 0) ? routerW[2 * n + 1] : 0.f;
    float ws = w0 + w1;
    const float* xr = x + (size_t)n * D_ + d0;
    float* orow = out + (size_t)n * D_ + d0;
    float4 a = *(const float4*)&xr[0];
    float4 b = *(const float4*)&xr[4];
    float4 oa, ob;
    oa.x = ws * a.x; oa.y = ws * a.y; oa.z = ws * a.z; oa.w = ws * a.w;
    ob.x = ws * b.x; ob.y = ws * b.y; ob.z = ws * b.z; ob.w = ws * b.w;
    *(float4*)&orow[0] = oa;
    *(float4*)&orow[4] = ob;
}

// ---------------------------------------------------------------------------
// Gather + RMSNorm: zE[pos] = bf16(2x*rsqrt(mean((2x)^2)+eps)*nw[e]).
// z rows beyond count written as zeros (so full 256-row GEMM tiles are valid).
// ---------------------------------------------------------------------------
__global__ __launch_bounds__(256) void gather_norm_kernel(
    const float* __restrict__ x, const float* __restrict__ norm_w,
    const int* __restrict__ slotToken, const int* __restrict__ cnt,
    u16* __restrict__ zAll, size_t zStride, int eFixed)
{
    int e = eFixed + blockIdx.z;
    u16* zE = zAll + (size_t)blockIdx.z * zStride;
    int t = threadIdx.x, wv = t >> 6, l = t & 63;
    int pos = blockIdx.x * 4 + wv;
    int ce = min(cnt[e], CAP);
    u16* zr = zE + (size_t)pos * D_;
    if (pos >= ce) {
        ushort4 zz = { 0, 0, 0, 0 };
#pragma unroll
        for (int j = 0; j < 3; ++j) *(ushort4*)&zr[l * 4 + 256 * j] = zz;
        return;
    }
    int tok = slotToken[e * CAP + pos] >> 1;
    const float* xr = x + (size_t)tok * D_;
    float xv[12]; float ss = 0.f;
#pragma unroll
    for (int j = 0; j < 3; ++j) {
        float4 v4 = *(const float4*)&xr[l * 4 + 256 * j];
        xv[4 * j] = v4.x; xv[4 * j + 1] = v4.y; xv[4 * j + 2] = v4.z; xv[4 * j + 3] = v4.w;
        ss += v4.x * v4.x + v4.y * v4.y + v4.z * v4.z + v4.w * v4.w;
    }
#pragma unroll
    for (int off = 32; off > 0; off >>= 1) ss += __shfl_xor(ss, off, 64);
    float rs = rsqrtf(4.f * ss * (1.f / (float)D_) + EPS_);
    const float* nw = norm_w + e * D_;
#pragma unroll
    for (int j = 0; j < 3; ++j) {
        int d0 = l * 4 + 256 * j;
        float4 nv = *(const float4*)&nw[d0];
        ushort4 o;
        o.x = f2bf(2.f * xv[4 * j]     * rs * nv.x);
        o.y = f2bf(2.f * xv[4 * j + 1] * rs * nv.y);
        o.z = f2bf(2.f * xv[4 * j + 2] * rs * nv.z);
        o.w = f2bf(2.f * xv[4 * j + 3] * rs * nv.w);
        *(ushort4*)&zr[d0] = o;
    }
}

// ---------------------------------------------------------------------------
// Deep-pipeline staging macro: 4 per-wave global_load_lds per K-tile.
// ---------------------------------------------------------------------------
#define STAGE(tk) do { int b3_ = (tk) & 3; size_t ko_ = (size_t)(tk) * 64; \
    u16* A_ = &lds[b3_][0][0]; u16* B_ = &lds[b3_][1][0]; \
    gload16(aS0 + ko_, A_ + w * 512); \
    gload16(aS1 + ko_, A_ + 4096 + w * 512); \
    gload16(bS0 + ko_, B_ + w * 512); \
    gload16(bS1 + ko_, B_ + 4096 + w * 512); } while (0)

#define PIPE_WAIT_BARRIER(tk, NT) do { \
    if ((tk) + 3 < (NT))      asm volatile("s_waitcnt vmcnt(8)" ::: "memory"); \
    else if ((tk) + 2 < (NT)) asm volatile("s_waitcnt vmcnt(4)" ::: "memory"); \
    else if ((tk) + 1 < (NT)) asm volatile("s_waitcnt vmcnt(0)" ::: "memory"); \
    if ((tk) + 1 < (NT)) { __builtin_amdgcn_s_barrier(); __builtin_amdgcn_sched_barrier(0); } } while (0)

// ---------------------------------------------------------------------------
// GEMM1: gu = zE @ w13e^T, tile 256 x (128g|128u interleaved by wave),
// BK=32, K=768 (24 K-tiles), 512 threads (8 waves, 2Mx4N), fused SwiGLU.
// ---------------------------------------------------------------------------
__global__ __launch_bounds__(512, 2) void gemm1_kernel(
    const u16* __restrict__ zAll, size_t zStride,
    const u16* __restrict__ w13All, size_t wStride,
    u16* __restrict__ actAll, size_t actStride,
    const int* __restrict__ cnt, int eFixed)
{
    // XCD chunk swizzle over the 16x20 plane (nwg=320): 4 jn x 10 rb per XCD
    int hw  = blockIdx.y * 16 + blockIdx.x;
    int xcd = hw & 7, cid = hw >> 3;            // cid in [0,40)
    int jn  = (xcd & 3) * 4 + (cid & 3);        // 0..15 (H block of 128)
    int rb  = (xcd >> 2) * 10 + (cid >> 2);     // 0..19 (row block of 256)
    int e   = eFixed + blockIdx.z;
    int ce  = min(cnt[e], CAP);
    if (rb * 256 >= ce) return;
    const u16* zE   = zAll   + (size_t)blockIdx.z * zStride;
    const u16* w13e = w13All + (size_t)blockIdx.z * wStride;
    u16*       actE = actAll + (size_t)blockIdx.z * actStride;

    __shared__ __align__(16) u16 lds[4][2][8192];   // 4 K-tile bufs x (A,B) x 16KB

    int t = threadIdx.x, w = t >> 6, l = t & 63;
    int wr = w >> 2, wc = w & 3;

    // staging source: row = t>>2 (+128 for chunk 1), 16B slot inv-swizzled
    int srow = t >> 2;
    int ssw  = (((t & 3) ^ ((t >> 3) & 3)) << 4);
    const char* aS0 = (const char*)(zE + (size_t)(rb * 256 + srow) * D_) + ssw;
    const char* aS1 = aS0 + (size_t)128 * D_ * 2;
    const char* bS0 = (const char*)(w13e + (size_t)(jn * 128 + srow) * D_) + ssw;          // g rows
    const char* bS1 = (const char*)(w13e + (size_t)(H_ + jn * 128 + srow) * D_) + ssw;     // u rows

    // fragment read offsets (read-side swizzle)
    int fr = l & 15, slot = l >> 4;
    int swz  = (slot ^ ((fr >> 1) & 3)) << 4;
    int aoff = (wr * 128 + fr) * 64 + swz;
    int boff = (wc * 32 + fr) * 64 + swz;

    const v4f vzero = { 0.f, 0.f, 0.f, 0.f };
    v4f acc[8][4];
#pragma unroll
    for (int i = 0; i < 8; ++i)
#pragma unroll
        for (int j = 0; j < 4; ++j) acc[i][j] = vzero;

    STAGE(0); STAGE(1); STAGE(2);
    asm volatile("s_waitcnt vmcnt(8)" ::: "memory");
    __builtin_amdgcn_s_barrier();
    __builtin_amdgcn_sched_barrier(0);

#pragma unroll 1
    for (int tk = 0; tk < 24; ++tk) {
        if (tk + 3 < 24) STAGE(tk + 3);
        __builtin_amdgcn_sched_barrier(0);
        const char* A3 = (const char*)&lds[tk & 3][0][0];
        const char* B3 = (const char*)&lds[tk & 3][1][0];
        v8bf bv[4], a0_[4], a1_[4];
#pragma unroll
        for (int cg = 0; cg < 4; ++cg)
            bv[cg] = *(const v8bf*)(B3 + boff + ((cg & 1) * 1024 + (cg >> 1) * 8192));
#pragma unroll
        for (int rg = 0; rg < 4; ++rg) a0_[rg] = *(const v8bf*)(A3 + aoff + rg * 1024);
        __builtin_amdgcn_s_setprio(1);
#pragma unroll
        for (int rg = 0; rg < 4; ++rg)
#pragma unroll
            for (int cg = 0; cg < 4; ++cg)
                acc[rg][cg] = __builtin_amdgcn_mfma_f32_16x16x32_bf16(a0_[rg], bv[cg], acc[rg][cg], 0, 0, 0);
        __builtin_amdgcn_s_setprio(0);
#pragma unroll
        for (int rg = 0; rg < 4; ++rg) a1_[rg] = *(const v8bf*)(A3 + aoff + (rg + 4) * 1024);
        __builtin_amdgcn_s_setprio(1);
#pragma unroll
        for (int rg = 0; rg < 4; ++rg)
#pragma unroll
            for (int cg = 0; cg < 4; ++cg)
                acc[rg + 4][cg] = __builtin_amdgcn_mfma_f32_16x16x32_bf16(a1_[rg], bv[cg], acc[rg + 4][cg], 0, 0, 0);
        __builtin_amdgcn_s_setprio(0);
        PIPE_WAIT_BARRIER(tk, 24);
    }

    // epilogue: silu(g)*u from f32 acc -> bf16 LDS (256x136) -> coalesced
    __syncthreads();
    u16* ep = (u16*)&lds[0][0][0];
    int rquad = (l >> 4) * 4;
#pragma unroll
    for (int rg = 0; rg < 8; ++rg) {
#pragma unroll
        for (int cg = 0; cg < 2; ++cg) {
            v4f g = acc[rg][cg], u = acc[rg][cg + 2];
#pragma unroll
            for (int r = 0; r < 4; ++r) {
                int row = wr * 128 + rg * 16 + rquad + r;
                int col = wc * 32 + cg * 16 + fr;
                float gv = g[r];
                ep[row * 136 + col] = f2bf(gv / (1.f + __expf(-gv)) * u[r]);
            }
        }
    }
    __syncthreads();
#pragma unroll
    for (int i = 0; i < 8; ++i) {
        int idx = i * 512 + t;
        int row = idx >> 4, c8 = (idx & 15) << 3;
        uint4 v = *(const uint4*)&ep[row * 136 + c8];
        *(uint4*)&actE[(size_t)(rb * 256 + row) * H_ + jn * 128 + c8] = v;
    }
}

// ---------------------------------------------------------------------------
// GEMM2: delta = actE @ w2e^T, tile 256 x 256, BK=32, K=2048 (64 K-tiles),
// 512 threads.  Epilogue in two 128-row halves through LDS (256x264).
// ---------------------------------------------------------------------------
template <bool WRITE_DELTA>
__global__ __launch_bounds__(512, 2) void gemm2_kernel(
    const u16* __restrict__ actAll, size_t actStride,
    const u16* __restrict__ w2All, size_t wStride,
    const int* __restrict__ slotToken, const float* __restrict__ routerW,
    float* __restrict__ out, u16* __restrict__ deltaAll, size_t deltaStride,
    const int* __restrict__ cnt, int eFixed)
{
    int jn = blockIdx.x;   // 0..2: cols [jn*256, +256)
    int rb = blockIdx.y;   // 0..19
    int e  = eFixed + blockIdx.z;
    int ce = min(cnt[e], CAP);
    if (rb * 256 >= ce) return;
    const u16* actE = actAll + (size_t)blockIdx.z * actStride;
    const u16* w2e  = w2All  + (size_t)blockIdx.z * wStride;

    __shared__ __align__(16) u16 lds[4][2][8192];

    int t = threadIdx.x, w = t >> 6, l = t & 63;
    int wr = w >> 2, wc = w & 3;

    int srow = t >> 2;
    int ssw  = (((t & 3) ^ ((t >> 3) & 3)) << 4);
    const char* aS0 = (const char*)(actE + (size_t)(rb * 256 + srow) * H_) + ssw;
    const char* aS1 = aS0 + (size_t)128 * H_ * 2;
    const char* bS0 = (const char*)(w2e + (size_t)(jn * 256 + srow) * H_) + ssw;
    const char* bS1 = bS0 + (size_t)128 * H_ * 2;

    int fr = l & 15, slot = l >> 4;
    int swz  = (slot ^ ((fr >> 1) & 3)) << 4;
    int aoff = (wr * 128 + fr) * 64 + swz;
    int boff = (wc * 64 + fr) * 64 + swz;

    const v4f vzero = { 0.f, 0.f, 0.f, 0.f };
    v4f acc[8][4];
#pragma unroll
    for (int i = 0; i < 8; ++i)
#pragma unroll
        for (int j = 0; j < 4; ++j) acc[i][j] = vzero;

    STAGE(0); STAGE(1); STAGE(2);
    asm volatile("s_waitcnt vmcnt(8)" ::: "memory");
    __builtin_amdgcn_s_barrier();
    __builtin_amdgcn_sched_barrier(0);

#pragma unroll 1
    for (int tk = 0; tk < 64; ++tk) {
        if (tk + 3 < 64) STAGE(tk + 3);
        __builtin_amdgcn_sched_barrier(0);
        const char* A3 = (const char*)&lds[tk & 3][0][0];
        const char* B3 = (const char*)&lds[tk & 3][1][0];
        v8bf bv[4], a0_[4], a1_[4];
#pragma unroll
        for (int cg = 0; cg < 4; ++cg)
            bv[cg] = *(const v8bf*)(B3 + boff + cg * 1024);
#pragma unroll
        for (int rg = 0; rg < 4; ++rg) a0_[rg] = *(const v8bf*)(A3 + aoff + rg * 1024);
        __builtin_amdgcn_s_setprio(1);
#pragma unroll
        for (int rg = 0; rg < 4; ++rg)
#pragma unroll
            for (int cg = 0; cg < 4; ++cg)
                acc[rg][cg] = __builtin_amdgcn_mfma_f32_16x16x32_bf16(a0_[rg], bv[cg], acc[rg][cg], 0, 0, 0);
        __builtin_amdgcn_s_setprio(0);
#pragma unroll
        for (int rg = 0; rg < 4; ++rg) a1_[rg] = *(const v8bf*)(A3 + aoff + (rg + 4) * 1024);
        __builtin_amdgcn_s_setprio(1);
#pragma unroll
        for (int rg = 0; rg < 4; ++rg)
#pragma unroll
            for (int cg = 0; cg < 4; ++cg)
                acc[rg + 4][cg] = __builtin_amdgcn_mfma_f32_16x16x32_bf16(a1_[rg], bv[cg], acc[rg + 4][cg], 0, 0, 0);
        __builtin_amdgcn_s_setprio(0);
        PIPE_WAIT_BARRIER(tk, 64);
    }

    // epilogue: two 128-row halves through LDS (stride 264 u16).
    __syncthreads();
    u16* ep = (u16*)&lds[0][0][0];
    int rquad = (l >> 4) * 4;
#pragma unroll
    for (int h = 0; h < 2; ++h) {
        if (h) __syncthreads();
        if (wr == h) {
#pragma unroll
            for (int rg = 0; rg < 8; ++rg) {
#pragma unroll
                for (int cg = 0; cg < 4; ++cg) {
                    v4f a = acc[rg][cg];
#pragma unroll
                    for (int r = 0; r < 4; ++r) {
                        int row = rg * 16 + rquad + r;
                        int col = wc * 64 + cg * 16 + fr;
                        ep[row * 264 + col] = f2bf(a[r]);
                    }
                }
            }
        }
        __syncthreads();
        if (WRITE_DELTA) {
            u16* deltaE = deltaAll + (size_t)blockIdx.z * deltaStride;
#pragma unroll
            for (int i = 0; i < 8; ++i) {
                int idx = i * 512 + t;
                int row = idx >> 5, c8 = (idx & 31) << 3;
                uint4 v = *(const uint4*)&ep[row * 264 + c8];
                *(uint4*)&deltaE[(size_t)(rb * 256 + h * 128 + row) * D_ + jn * 256 + c8] = v;
            }
        } else {
            // fp32 RMW into out rows (experts serialized -> race-free)
#pragma unroll
            for (int i = 0; i < 16; ++i) {
                int idx = i * 512 + t;
                int row = idx >> 6, c = (idx & 63) << 2;
                int grow = rb * 256 + h * 128 + row;
                if (grow >= ce) continue;
                int sidx = slotToken[e * CAP + grow];
                int tok = sidx >> 1;
                float wg = routerW[sidx];
                const u16* dr = &ep[row * 264 + c];
                float* orow = out + (size_t)tok * D_ + jn * 256 + c;
                float4 cur = *(const float4*)orow;
                cur.x += wg * bf2f(dr[0]);
                cur.y += wg * bf2f(dr[1]);
                cur.z += wg * bf2f(dr[2]);
                cur.w += wg * bf2f(dr[3]);
                *(float4*)orow = cur;
            }
        }
    }
}

// ---------------------------------------------------------------------------
// Combine (batched path): out[n] = ws*x[n] + w0*delta[s0] + w1*delta[s1]
// ---------------------------------------------------------------------------
__global__ __launch_bounds__(256) void combine_kernel(
    const float* __restrict__ x, const u16* __restrict__ deltaBuf,
    const int* __restrict__ tokenSlot, const float* __restrict__ routerW,
    float* __restrict__ out)
{
    int g = blockIdx.x * 256 + threadIdx.x;  // one float4 per thread
    int n = g / 192;
    int d0 = (g - n * 192) * 4;
    int s0 = tokenSlot[2 * n], s1 = tokenSlot[2 * n + 1];
    float w0 = (s0 >= 0) ? routerW[2 * n] : 0.f;
    float w1 = (s1 >= 0) ? routerW[2 * n + 1] : 0.f;
    float ws = w0 + w1;
    float4 xv = *(const float4*)&x[(size_t)n * D_ + d0];
    float4 o;
    o.x = ws * xv.x; o.y = ws * xv.y; o.z = ws * xv.z; o.w = ws * xv.w;
    if (s0 >= 0) {
        ushort4 dv = *(const ushort4*)&deltaBuf[(size_t)s0 * D_ + d0];
        o.x += w0 * bf2f(dv.x); o.y += w0 * bf2f(dv.y);
        o.z += w0 * bf2f(dv.z); o.w += w0 * bf2f(dv.w);
    }
    if (s1 >= 0) {
        ushort4 dv = *(const ushort4*)&deltaBuf[(size_t)s1 * D_ + d0];
        o.x += w1 * bf2f(dv.x); o.y += w1 * bf2f(dv.y);
        o.z += w1 * bf2f(dv.z); o.w += w1 * bf2f(dv.w);
    }
    *(float4*)&out[(size_t)n * D_ + d0] = o;
}

// ---------------------------------------------------------------------------
extern "C" void kernel_launch(void* const* d_in, const int* in_sizes, int n_in,
                              void* d_out, int out_size, void* d_ws, size_t ws_size,
                              hipStream_t stream)
{
    (void)in_sizes; (void)n_in; (void)out_size;
    const float* x      = (const float*)d_in[0];
    const float* gate_w = (const float*)d_in[1];
    const float* w13    = (const float*)d_in[2];
    const float* w2     = (const float*)d_in[3];
    const float* norm_w = (const float*)d_in[4];
    float* out = (float*)d_out;

    const size_t zSlice   = (size_t)CAP * D_ * 2;       // 7.9 MB
    const size_t actSlice = (size_t)CAP * H_ * 2;       // 21 MB
    const size_t w13Slice = (size_t)2 * H_ * D_ * 2;    // 12.6 MB
    const size_t w2Slice  = (size_t)D_ * H_ * 2;        // 3.1 MB
    const size_t ctrl     = (size_t)NK * 4 * 3 + (size_t)E_ * CAP * 4 + 256;

    char* ws = (char*)d_ws;
    size_t off = 0;
    int*   routerEx  = (int*)(ws + off);   off += (size_t)NK * 4;
    float* routerW   = (float*)(ws + off); off += (size_t)NK * 4;
    int*   tokenSlot = (int*)(ws + off);   off += (size_t)NK * 4;
    int*   slotToken = (int*)(ws + off);   off += (size_t)E_ * CAP * 4;
    int*   cnt       = (int*)(ws + off);   off += 256;

    const size_t bigNeed = ctrl + E_ * (zSlice + actSlice + w13Slice + w2Slice) + E_ * zSlice /*delta*/;
    bool batched = ws_size >= bigNeed;

    router_kernel<<<N_TOK / 4, 256, 0, stream>>>(x, gate_w, routerEx, routerW);
    dispatch_kernel<<<1, 256, 0, stream>>>(routerEx, tokenSlot, slotToken, cnt);

    if (batched) {
        u16* zBuf     = (u16*)(ws + off); off += E_ * zSlice;
        u16* actBuf   = (u16*)(ws + off); off += E_ * actSlice;
        u16* deltaBuf = (u16*)(ws + off); off += E_ * zSlice;
        u16* w13bf    = (u16*)(ws + off); off += E_ * w13Slice;
        u16* w2bf     = (u16*)(ws + off); off += E_ * w2Slice;

        int n13 = E_ * 2 * H_ * D_ / 4, n2 = E_ * D_ * H_ / 4;
        conv_bf16_kernel<<<(n13 + 255) / 256, 256, 0, stream>>>(w13, w13bf, n13);
        conv_bf16_kernel<<<(n2 + 255) / 256, 256, 0, stream>>>(w2, w2bf, n2);
        gather_norm_kernel<<<dim3(CAP / 4, 1, E_), 256, 0, stream>>>(
            x, norm_w, slotToken, cnt, zBuf, zSlice / 2, 0);
        gemm1_kernel<<<dim3(16, CAP / 256, E_), 512, 0, stream>>>(
            zBuf, zSlice / 2, w13bf, w13Slice / 2, actBuf, actSlice / 2, cnt, 0);
        gemm2_kernel<true><<<dim3(3, CAP / 256, E_), 512, 0, stream>>>(
            actBuf, actSlice / 2, w2bf, w2Slice / 2, slotToken, routerW,
            out, deltaBuf, zSlice / 2, cnt, 0);
        combine_kernel<<<(N_TOK * (D_ / 4)) / 256, 256, 0, stream>>>(
            x, deltaBuf, tokenSlot, routerW, out);
    } else {
        u16* zE   = (u16*)(ws + off); off += zSlice;
        u16* actE = (u16*)(ws + off); off += actSlice;
        u16* w13e = (u16*)(ws + off); off += w13Slice;
        u16* w2e  = (u16*)(ws + off); off += w2Slice;

        init_out_kernel<<<(N_TOK * (D_ / 8)) / 256, 256, 0, stream>>>(x, tokenSlot, routerW, out);
        int n13 = 2 * H_ * D_ / 4, n2 = D_ * H_ / 4;
        for (int e = 0; e < E_; ++e) {
            conv_bf16_kernel<<<(n13 + 255) / 256, 256, 0, stream>>>(
                w13 + (size_t)e * 2 * H_ * D_, w13e, n13);
            conv_bf16_kernel<<<(n2 + 255) / 256, 256, 0, stream>>>(
                w2 + (size_t)e * D_ * H_, w2e, n2);
            gather_norm_kernel<<<dim3(CAP / 4, 1, 1), 256, 0, stream>>>(
                x, norm_w, slotToken, cnt, zE, 0, e);
            gemm1_kernel<<<dim3(16, CAP / 256, 1), 512, 0, stream>>>(
                zE, 0, w13e, 0, actE, 0, cnt, e);
            gemm2_kernel<false><<<dim3(3, CAP / 256, 1), 512, 0, stream>>>(
                actE, 0, w2e, 0, slotToken, routerW, out, (u16*)nullptr, 0, cnt, e);
        }
    }
}

// Round 4
// 743.504 us; speedup vs baseline: 1.0074x; 1.0074x over previous
//
#include <hip/hip_runtime.h>
#include <hip/hip_bf16.h>
#include <stdint.h>

// ---------------------------------------------------------------------------
// MoE top-2 with capacity, per-expert RMSNorm + SwiGLU FFN.  fp32 I/O,
// bf16 MFMA internals.  N=16384, D=768, E=8, H=2048, CAP=5120.
// Round 9: fine-grained 2-phase-per-K-tile schedule (the m196/m218 lever
// R2's coarse split was missing):
//   per K-tile t (BK=32, 4 LDS bufs, prefetch dist 3):
//     phase0: ds_read 4 B-frags + 4 A-frags | issue A-half stage of t+3
//             | s_barrier | lgkmcnt(0)+sched_barrier | setprio(1) 16 MFMA
//     phase1: ds_read 4 A-frags             | issue B-half stage of t+3
//             | s_barrier | lgkmcnt(0)+sched_barrier | setprio(1) 16 MFMA
//             | vmcnt(8) ramp | s_barrier
//   Counted vmcnt: tiles t+2,t+3 (8 loads) stay in flight across barriers.
//   WAR-safe: stage target buf[(t+3)&3] was last read at iter t-1.
// Carried: global_load_lds(16B), both-sides XOR swizzle, XCD chunk swizzle,
// LDS round-trip epilogues, LDS-staged dispatch.
// ---------------------------------------------------------------------------

#define N_TOK 16384
#define D_    768
#define E_    8
#define H_    2048
#define CAP   5120
#define NK    (N_TOK * 2)
#define EPS_  1e-6f

typedef unsigned short u16;
typedef unsigned char  u8;
typedef __attribute__((ext_vector_type(8))) __bf16 v8bf;
typedef __attribute__((ext_vector_type(4))) float  v4f;

typedef __attribute__((address_space(3))) unsigned int lds_u32;
typedef const __attribute__((address_space(1))) unsigned int glb_u32;

__device__ __forceinline__ void gload16(const void* g, void* lds) {
    __builtin_amdgcn_global_load_lds((glb_u32*)g, (lds_u32*)lds, 16, 0, 0);
}

__device__ __forceinline__ float bf2f(u16 u) {
    union { uint32_t i; float f; } v; v.i = ((uint32_t)u) << 16; return v.f;
}
__device__ __forceinline__ u16 f2bf(float f) {
    union { uint32_t i; float f; } v; v.f = f;
    uint32_t r = v.i + 0x7fffu + ((v.i >> 16) & 1u);
    return (u16)(r >> 16);
}

// ---------------------------------------------------------------------------
// fp32 -> bf16 weight conversion, float4 granularity, grid-stride.
// ---------------------------------------------------------------------------
__global__ __launch_bounds__(256) void conv_bf16_kernel(
    const float* __restrict__ src, u16* __restrict__ dst, int n4)
{
    for (int i = blockIdx.x * 256 + threadIdx.x; i < n4; i += gridDim.x * 256) {
        float4 v = ((const float4*)src)[i];
        ushort4 o;
        o.x = f2bf(v.x); o.y = f2bf(v.y); o.z = f2bf(v.z); o.w = f2bf(v.w);
        ((ushort4*)dst)[i] = o;
    }
}

// ---------------------------------------------------------------------------
// Router: one wave per token; top-2; w0 = 1/(1+exp(l1-l0)).
// ---------------------------------------------------------------------------
__global__ __launch_bounds__(256) void router_kernel(
    const float* __restrict__ x, const float* __restrict__ gate_w,
    int* __restrict__ routerEx, float* __restrict__ routerW)
{
    __shared__ float gw[E_ * D_];
    int t = threadIdx.x;
    for (int i = t; i < E_ * D_; i += 256) gw[i] = gate_w[i];
    __syncthreads();
    int wv = t >> 6, l = t & 63;
    int n = blockIdx.x * 4 + wv;
    const float* xr = x + (size_t)n * D_;
    float p[E_];
#pragma unroll
    for (int e = 0; e < E_; ++e) p[e] = 0.f;
#pragma unroll
    for (int j = 0; j < 12; ++j) {
        int d = l + 64 * j;
        float xv = xr[d];
#pragma unroll
        for (int e = 0; e < E_; ++e) p[e] += xv * gw[e * D_ + d];
    }
#pragma unroll
    for (int off = 32; off > 0; off >>= 1) {
#pragma unroll
        for (int e = 0; e < E_; ++e) p[e] += __shfl_xor(p[e], off, 64);
    }
    if (l == 0) {
        int e0 = 0; float m0 = p[0];
#pragma unroll
        for (int e = 1; e < E_; ++e) if (p[e] > m0) { m0 = p[e]; e0 = e; }
        int e1 = (e0 == 0) ? 1 : 0; float m1 = p[e1];
#pragma unroll
        for (int e = 0; e < E_; ++e) if (e != e0 && p[e] > m1) { m1 = p[e]; e1 = e; }
        float w0 = 1.f / (1.f + __expf(m1 - m0));
        routerEx[2 * n] = e0; routerEx[2 * n + 1] = e1;
        routerW[2 * n] = w0; routerW[2 * n + 1] = 1.f - w0;
    }
}

// ---------------------------------------------------------------------------
// Dispatch: exact token-major (i = n*2+k) capacity ranking, single block.
// ---------------------------------------------------------------------------
__global__ __launch_bounds__(256) void dispatch_kernel(
    const int* __restrict__ routerEx, int* __restrict__ tokenSlot,
    int* __restrict__ slotToken, int* __restrict__ cnt)
{
    __shared__ u8  exs[NK + NK / 128];   // 33 KB
    __shared__ int hist[256 * E_];       // 8 KB
    int t = threadIdx.x;
    for (int i = t; i < NK; i += 256)
        exs[i + (i >> 7)] = (u8)routerEx[i];
    __syncthreads();
    int loc[E_];
#pragma unroll
    for (int e = 0; e < E_; ++e) loc[e] = 0;
    int abase = t * 129;                 // t*128 + pad(t)
    for (int j = 0; j < NK / 256; ++j) {
        int ev = exs[abase + j];
#pragma unroll
        for (int e = 0; e < E_; ++e) loc[e] += (ev == e) ? 1 : 0;
    }
#pragma unroll
    for (int e = 0; e < E_; ++e) hist[t * E_ + e] = loc[e];
    __syncthreads();
    if (t < E_) {
        int run = 0;
        for (int tt = 0; tt < 256; ++tt) { int v = hist[tt * E_ + t]; hist[tt * E_ + t] = run; run += v; }
        cnt[t] = run;
    }
    __syncthreads();
    int off[E_];
#pragma unroll
    for (int e = 0; e < E_; ++e) off[e] = hist[t * E_ + e];
    int base = t * (NK / 256);
    for (int j = 0; j < NK / 256; ++j) {
        int i = base + j;
        int ev = exs[abase + j];
        int pos = 0;
#pragma unroll
        for (int e = 0; e < E_; ++e) { if (ev == e) { pos = off[e]; off[e] = pos + 1; } }
        if (pos < CAP) {
            int s = ev * CAP + pos;
            tokenSlot[i] = s;
            slotToken[s] = i;
        } else {
            tokenSlot[i] = -1;
        }
    }
}

// ---------------------------------------------------------------------------
// init_out: out[n] = (sum kept w) * x[n]   (per-expert path only)
// ---------------------------------------------------------------------------
__global__ __launch_bounds__(256) void init_out_kernel(
    const float* __restrict__ x, const int* __restrict__ tokenSlot,
    const float* __restrict__ routerW, float* __restrict__ out)
{
    int g = blockIdx.x * 256 + threadIdx.x;
    int n = g / 96;
    int d0 = (g - n * 96) * 8;
    float w0 = (tokenSlot[2 * n] >= 0) ? routerW[2 * n] : 0.f;
    float w1 = (tokenSlot[2 * n + 1] >= 0) ? routerW[2 * n + 1] : 0.f;
    float ws = w0 + w1;
    const float* xr = x + (size_t)n * D_ + d0;
    float* orow = out + (size_t)n * D_ + d0;
    float4 a = *(const float4*)&xr[0];
    float4 b = *(const float4*)&xr[4];
    float4 oa, ob;
    oa.x = ws * a.x; oa.y = ws * a.y; oa.z = ws * a.z; oa.w = ws * a.w;
    ob.x = ws * b.x; ob.y = ws * b.y; ob.z = ws * b.z; ob.w = ws * b.w;
    *(float4*)&orow[0] = oa;
    *(float4*)&orow[4] = ob;
}

// ---------------------------------------------------------------------------
// Gather + RMSNorm: zE[pos] = bf16(2x*rsqrt(mean((2x)^2)+eps)*nw[e]).
// z rows beyond count written as zeros (so full 256-row GEMM tiles are valid).
// ---------------------------------------------------------------------------
__global__ __launch_bounds__(256) void gather_norm_kernel(
    const float* __restrict__ x, const float* __restrict__ norm_w,
    const int* __restrict__ slotToken, const int* __restrict__ cnt,
    u16* __restrict__ zAll, size_t zStride, int eFixed)
{
    int e = eFixed + blockIdx.z;
    u16* zE = zAll + (size_t)blockIdx.z * zStride;
    int t = threadIdx.x, wv = t >> 6, l = t & 63;
    int pos = blockIdx.x * 4 + wv;
    int ce = min(cnt[e], CAP);
    u16* zr = zE + (size_t)pos * D_;
    if (pos >= ce) {
        ushort4 zz = { 0, 0, 0, 0 };
#pragma unroll
        for (int j = 0; j < 3; ++j) *(ushort4*)&zr[l * 4 + 256 * j] = zz;
        return;
    }
    int tok = slotToken[e * CAP + pos] >> 1;
    const float* xr = x + (size_t)tok * D_;
    float xv[12]; float ss = 0.f;
#pragma unroll
    for (int j = 0; j < 3; ++j) {
        float4 v4 = *(const float4*)&xr[l * 4 + 256 * j];
        xv[4 * j] = v4.x; xv[4 * j + 1] = v4.y; xv[4 * j + 2] = v4.z; xv[4 * j + 3] = v4.w;
        ss += v4.x * v4.x + v4.y * v4.y + v4.z * v4.z + v4.w * v4.w;
    }
#pragma unroll
    for (int off = 32; off > 0; off >>= 1) ss += __shfl_xor(ss, off, 64);
    float rs = rsqrtf(4.f * ss * (1.f / (float)D_) + EPS_);
    const float* nw = norm_w + e * D_;
#pragma unroll
    for (int j = 0; j < 3; ++j) {
        int d0 = l * 4 + 256 * j;
        float4 nv = *(const float4*)&nw[d0];
        ushort4 o;
        o.x = f2bf(2.f * xv[4 * j]     * rs * nv.x);
        o.y = f2bf(2.f * xv[4 * j + 1] * rs * nv.y);
        o.z = f2bf(2.f * xv[4 * j + 2] * rs * nv.z);
        o.w = f2bf(2.f * xv[4 * j + 3] * rs * nv.w);
        *(ushort4*)&zr[d0] = o;
    }
}

// ---------------------------------------------------------------------------
// Pipeline helper macros (BK=32, 4 bufs, dist-3).
// ---------------------------------------------------------------------------
#define STAGE_A(tk) do { int b3_ = (tk) & 3; size_t ko_ = (size_t)(tk) * 64; \
    u16* A_ = &lds[b3_][0][0]; \
    gload16(aS0 + ko_, A_ + w * 512); \
    gload16(aS1 + ko_, A_ + 4096 + w * 512); } while (0)

#define STAGE_B(tk) do { int b3_ = (tk) & 3; size_t ko_ = (size_t)(tk) * 64; \
    u16* B_ = &lds[b3_][1][0]; \
    gload16(bS0 + ko_, B_ + w * 512); \
    gload16(bS1 + ko_, B_ + 4096 + w * 512); } while (0)

#define PHASE_SYNC() do { \
    __builtin_amdgcn_s_barrier(); \
    asm volatile("s_waitcnt lgkmcnt(0)" ::: "memory"); \
    __builtin_amdgcn_sched_barrier(0); } while (0)

#define PIPE_WAIT_BARRIER(tk, NT) do { \
    if ((tk) + 3 < (NT))      asm volatile("s_waitcnt vmcnt(8)" ::: "memory"); \
    else if ((tk) + 2 < (NT)) asm volatile("s_waitcnt vmcnt(4)" ::: "memory"); \
    else if ((tk) + 1 < (NT)) asm volatile("s_waitcnt vmcnt(0)" ::: "memory"); \
    if ((tk) + 1 < (NT)) { __builtin_amdgcn_s_barrier(); __builtin_amdgcn_sched_barrier(0); } } while (0)

// ---------------------------------------------------------------------------
// GEMM1: gu = zE @ w13e^T, tile 256 x (128g|128u by wave), BK=32, K=768
// (24 K-tiles), 512 threads (8 waves, 2Mx4N), fused SwiGLU.
// ---------------------------------------------------------------------------
__global__ __launch_bounds__(512, 2) void gemm1_kernel(
    const u16* __restrict__ zAll, size_t zStride,
    const u16* __restrict__ w13All, size_t wStride,
    u16* __restrict__ actAll, size_t actStride,
    const int* __restrict__ cnt, int eFixed)
{
    // XCD chunk swizzle over the 16x20 plane (nwg=320): 4 jn x 10 rb per XCD
    int hw  = blockIdx.y * 16 + blockIdx.x;
    int xcd = hw & 7, cid = hw >> 3;            // cid in [0,40)
    int jn  = (xcd & 3) * 4 + (cid & 3);        // 0..15 (H block of 128)
    int rb  = (xcd >> 2) * 10 + (cid >> 2);     // 0..19 (row block of 256)
    int e   = eFixed + blockIdx.z;
    int ce  = min(cnt[e], CAP);
    if (rb * 256 >= ce) return;
    const u16* zE   = zAll   + (size_t)blockIdx.z * zStride;
    const u16* w13e = w13All + (size_t)blockIdx.z * wStride;
    u16*       actE = actAll + (size_t)blockIdx.z * actStride;

    __shared__ __align__(16) u16 lds[4][2][8192];   // 4 K-tile bufs x (A,B) x 16KB

    int t = threadIdx.x, w = t >> 6, l = t & 63;
    int wr = w >> 2, wc = w & 3;

    int srow = t >> 2;
    int ssw  = (((t & 3) ^ ((t >> 3) & 3)) << 4);
    const char* aS0 = (const char*)(zE + (size_t)(rb * 256 + srow) * D_) + ssw;
    const char* aS1 = aS0 + (size_t)128 * D_ * 2;
    const char* bS0 = (const char*)(w13e + (size_t)(jn * 128 + srow) * D_) + ssw;          // g rows
    const char* bS1 = (const char*)(w13e + (size_t)(H_ + jn * 128 + srow) * D_) + ssw;     // u rows

    int fr = l & 15, slot = l >> 4;
    int swz  = (slot ^ ((fr >> 1) & 3)) << 4;
    int aoff = (wr * 128 + fr) * 64 + swz;
    int boff = (wc * 32 + fr) * 64 + swz;

    const v4f vzero = { 0.f, 0.f, 0.f, 0.f };
    v4f acc[8][4];
#pragma unroll
    for (int i = 0; i < 8; ++i)
#pragma unroll
        for (int j = 0; j < 4; ++j) acc[i][j] = vzero;

    STAGE_A(0); STAGE_B(0); STAGE_A(1); STAGE_B(1); STAGE_A(2); STAGE_B(2);
    asm volatile("s_waitcnt vmcnt(8)" ::: "memory");
    __builtin_amdgcn_s_barrier();
    __builtin_amdgcn_sched_barrier(0);

#pragma unroll 1
    for (int tk = 0; tk < 24; ++tk) {
        const char* A3 = (const char*)&lds[tk & 3][0][0];
        const char* B3 = (const char*)&lds[tk & 3][1][0];
        v8bf bv[4], a0_[4], a1_[4];
        // ---- phase 0: B frags + A rg 0..3 | A-half stage ----
#pragma unroll
        for (int cg = 0; cg < 4; ++cg)
            bv[cg] = *(const v8bf*)(B3 + boff + ((cg & 1) * 1024 + (cg >> 1) * 8192));
#pragma unroll
        for (int rg = 0; rg < 4; ++rg) a0_[rg] = *(const v8bf*)(A3 + aoff + rg * 1024);
        if (tk + 3 < 24) STAGE_A(tk + 3);
        PHASE_SYNC();
        __builtin_amdgcn_s_setprio(1);
#pragma unroll
        for (int rg = 0; rg < 4; ++rg)
#pragma unroll
            for (int cg = 0; cg < 4; ++cg)
                acc[rg][cg] = __builtin_amdgcn_mfma_f32_16x16x32_bf16(a0_[rg], bv[cg], acc[rg][cg], 0, 0, 0);
        __builtin_amdgcn_s_setprio(0);
        __builtin_amdgcn_s_barrier();
        // ---- phase 1: A rg 4..7 | B-half stage ----
#pragma unroll
        for (int rg = 0; rg < 4; ++rg) a1_[rg] = *(const v8bf*)(A3 + aoff + (rg + 4) * 1024);
        if (tk + 3 < 24) STAGE_B(tk + 3);
        PHASE_SYNC();
        __builtin_amdgcn_s_setprio(1);
#pragma unroll
        for (int rg = 0; rg < 4; ++rg)
#pragma unroll
            for (int cg = 0; cg < 4; ++cg)
                acc[rg + 4][cg] = __builtin_amdgcn_mfma_f32_16x16x32_bf16(a1_[rg], bv[cg], acc[rg + 4][cg], 0, 0, 0);
        __builtin_amdgcn_s_setprio(0);
        PIPE_WAIT_BARRIER(tk, 24);
    }

    // epilogue: silu(g)*u from f32 acc -> bf16 LDS (256x136) -> coalesced
    __syncthreads();
    u16* ep = (u16*)&lds[0][0][0];
    int rquad = (l >> 4) * 4;
#pragma unroll
    for (int rg = 0; rg < 8; ++rg) {
#pragma unroll
        for (int cg = 0; cg < 2; ++cg) {
            v4f g = acc[rg][cg], u = acc[rg][cg + 2];
#pragma unroll
            for (int r = 0; r < 4; ++r) {
                int row = wr * 128 + rg * 16 + rquad + r;
                int col = wc * 32 + cg * 16 + fr;
                float gv = g[r];
                ep[row * 136 + col] = f2bf(gv / (1.f + __expf(-gv)) * u[r]);
            }
        }
    }
    __syncthreads();
#pragma unroll
    for (int i = 0; i < 8; ++i) {
        int idx = i * 512 + t;
        int row = idx >> 4, c8 = (idx & 15) << 3;
        uint4 v = *(const uint4*)&ep[row * 136 + c8];
        *(uint4*)&actE[(size_t)(rb * 256 + row) * H_ + jn * 128 + c8] = v;
    }
}

// ---------------------------------------------------------------------------
// GEMM2: delta = actE @ w2e^T, tile 256 x 256, BK=32, K=2048 (64 K-tiles),
// 512 threads.  Epilogue in two 128-row halves through LDS (256x264).
// ---------------------------------------------------------------------------
template <bool WRITE_DELTA>
__global__ __launch_bounds__(512, 2) void gemm2_kernel(
    const u16* __restrict__ actAll, size_t actStride,
    const u16* __restrict__ w2All, size_t wStride,
    const int* __restrict__ slotToken, const float* __restrict__ routerW,
    float* __restrict__ out, u16* __restrict__ deltaAll, size_t deltaStride,
    const int* __restrict__ cnt, int eFixed)
{
    int jn = blockIdx.x;   // 0..2: cols [jn*256, +256)
    int rb = blockIdx.y;   // 0..19
    int e  = eFixed + blockIdx.z;
    int ce = min(cnt[e], CAP);
    if (rb * 256 >= ce) return;
    const u16* actE = actAll + (size_t)blockIdx.z * actStride;
    const u16* w2e  = w2All  + (size_t)blockIdx.z * wStride;

    __shared__ __align__(16) u16 lds[4][2][8192];

    int t = threadIdx.x, w = t >> 6, l = t & 63;
    int wr = w >> 2, wc = w & 3;

    int srow = t >> 2;
    int ssw  = (((t & 3) ^ ((t >> 3) & 3)) << 4);
    const char* aS0 = (const char*)(actE + (size_t)(rb * 256 + srow) * H_) + ssw;
    const char* aS1 = aS0 + (size_t)128 * H_ * 2;
    const char* bS0 = (const char*)(w2e + (size_t)(jn * 256 + srow) * H_) + ssw;
    const char* bS1 = bS0 + (size_t)128 * H_ * 2;

    int fr = l & 15, slot = l >> 4;
    int swz  = (slot ^ ((fr >> 1) & 3)) << 4;
    int aoff = (wr * 128 + fr) * 64 + swz;
    int boff = (wc * 64 + fr) * 64 + swz;

    const v4f vzero = { 0.f, 0.f, 0.f, 0.f };
    v4f acc[8][4];
#pragma unroll
    for (int i = 0; i < 8; ++i)
#pragma unroll
        for (int j = 0; j < 4; ++j) acc[i][j] = vzero;

    STAGE_A(0); STAGE_B(0); STAGE_A(1); STAGE_B(1); STAGE_A(2); STAGE_B(2);
    asm volatile("s_waitcnt vmcnt(8)" ::: "memory");
    __builtin_amdgcn_s_barrier();
    __builtin_amdgcn_sched_barrier(0);

#pragma unroll 1
    for (int tk = 0; tk < 64; ++tk) {
        const char* A3 = (const char*)&lds[tk & 3][0][0];
        const char* B3 = (const char*)&lds[tk & 3][1][0];
        v8bf bv[4], a0_[4], a1_[4];
        // ---- phase 0 ----
#pragma unroll
        for (int cg = 0; cg < 4; ++cg)
            bv[cg] = *(const v8bf*)(B3 + boff + cg * 1024);
#pragma unroll
        for (int rg = 0; rg < 4; ++rg) a0_[rg] = *(const v8bf*)(A3 + aoff + rg * 1024);
        if (tk + 3 < 64) STAGE_A(tk + 3);
        PHASE_SYNC();
        __builtin_amdgcn_s_setprio(1);
#pragma unroll
        for (int rg = 0; rg < 4; ++rg)
#pragma unroll
            for (int cg = 0; cg < 4; ++cg)
                acc[rg][cg] = __builtin_amdgcn_mfma_f32_16x16x32_bf16(a0_[rg], bv[cg], acc[rg][cg], 0, 0, 0);
        __builtin_amdgcn_s_setprio(0);
        __builtin_amdgcn_s_barrier();
        // ---- phase 1 ----
#pragma unroll
        for (int rg = 0; rg < 4; ++rg) a1_[rg] = *(const v8bf*)(A3 + aoff + (rg + 4) * 1024);
        if (tk + 3 < 64) STAGE_B(tk + 3);
        PHASE_SYNC();
        __builtin_amdgcn_s_setprio(1);
#pragma unroll
        for (int rg = 0; rg < 4; ++rg)
#pragma unroll
            for (int cg = 0; cg < 4; ++cg)
                acc[rg + 4][cg] = __builtin_amdgcn_mfma_f32_16x16x32_bf16(a1_[rg], bv[cg], acc[rg + 4][cg], 0, 0, 0);
        __builtin_amdgcn_s_setprio(0);
        PIPE_WAIT_BARRIER(tk, 64);
    }

    // epilogue: two 128-row halves through LDS (stride 264 u16).
    __syncthreads();
    u16* ep = (u16*)&lds[0][0][0];
    int rquad = (l >> 4) * 4;
#pragma unroll
    for (int h = 0; h < 2; ++h) {
        if (h) __syncthreads();
        if (wr == h) {
#pragma unroll
            for (int rg = 0; rg < 8; ++rg) {
#pragma unroll
                for (int cg = 0; cg < 4; ++cg) {
                    v4f a = acc[rg][cg];
#pragma unroll
                    for (int r = 0; r < 4; ++r) {
                        int row = rg * 16 + rquad + r;
                        int col = wc * 64 + cg * 16 + fr;
                        ep[row * 264 + col] = f2bf(a[r]);
                    }
                }
            }
        }
        __syncthreads();
        if (WRITE_DELTA) {
            u16* deltaE = deltaAll + (size_t)blockIdx.z * deltaStride;
#pragma unroll
            for (int i = 0; i < 8; ++i) {
                int idx = i * 512 + t;
                int row = idx >> 5, c8 = (idx & 31) << 3;
                uint4 v = *(const uint4*)&ep[row * 264 + c8];
                *(uint4*)&deltaE[(size_t)(rb * 256 + h * 128 + row) * D_ + jn * 256 + c8] = v;
            }
        } else {
            // fp32 RMW into out rows (experts serialized -> race-free)
#pragma unroll
            for (int i = 0; i < 16; ++i) {
                int idx = i * 512 + t;
                int row = idx >> 6, c = (idx & 63) << 2;
                int grow = rb * 256 + h * 128 + row;
                if (grow >= ce) continue;
                int sidx = slotToken[e * CAP + grow];
                int tok = sidx >> 1;
                float wg = routerW[sidx];
                const u16* dr = &ep[row * 264 + c];
                float* orow = out + (size_t)tok * D_ + jn * 256 + c;
                float4 cur = *(const float4*)orow;
                cur.x += wg * bf2f(dr[0]);
                cur.y += wg * bf2f(dr[1]);
                cur.z += wg * bf2f(dr[2]);
                cur.w += wg * bf2f(dr[3]);
                *(float4*)orow = cur;
            }
        }
    }
}

// ---------------------------------------------------------------------------
// Combine (batched path): out[n] = ws*x[n] + w0*delta[s0] + w1*delta[s1]
// ---------------------------------------------------------------------------
__global__ __launch_bounds__(256) void combine_kernel(
    const float* __restrict__ x, const u16* __restrict__ deltaBuf,
    const int* __restrict__ tokenSlot, const float* __restrict__ routerW,
    float* __restrict__ out)
{
    int g = blockIdx.x * 256 + threadIdx.x;  // one float4 per thread
    int n = g / 192;
    int d0 = (g - n * 192) * 4;
    int s0 = tokenSlot[2 * n], s1 = tokenSlot[2 * n + 1];
    float w0 = (s0 >= 0) ? routerW[2 * n] : 0.f;
    float w1 = (s1 >= 0) ? routerW[2 * n + 1] : 0.f;
    float ws = w0 + w1;
    float4 xv = *(const float4*)&x[(size_t)n * D_ + d0];
    float4 o;
    o.x = ws * xv.x; o.y = ws * xv.y; o.z = ws * xv.z; o.w = ws * xv.w;
    if (s0 >= 0) {
        ushort4 dv = *(const ushort4*)&deltaBuf[(size_t)s0 * D_ + d0];
        o.x += w0 * bf2f(dv.x); o.y += w0 * bf2f(dv.y);
        o.z += w0 * bf2f(dv.z); o.w += w0 * bf2f(dv.w);
    }
    if (s1 >= 0) {
        ushort4 dv = *(const ushort4*)&deltaBuf[(size_t)s1 * D_ + d0];
        o.x += w1 * bf2f(dv.x); o.y += w1 * bf2f(dv.y);
        o.z += w1 * bf2f(dv.z); o.w += w1 * bf2f(dv.w);
    }
    *(float4*)&out[(size_t)n * D_ + d0] = o;
}

// ---------------------------------------------------------------------------
extern "C" void kernel_launch(void* const* d_in, const int* in_sizes, int n_in,
                              void* d_out, int out_size, void* d_ws, size_t ws_size,
                              hipStream_t stream)
{
    (void)in_sizes; (void)n_in; (void)out_size;
    const float* x      = (const float*)d_in[0];
    const float* gate_w = (const float*)d_in[1];
    const float* w13    = (const float*)d_in[2];
    const float* w2     = (const float*)d_in[3];
    const float* norm_w = (const float*)d_in[4];
    float* out = (float*)d_out;

    const size_t zSlice   = (size_t)CAP * D_ * 2;       // 7.9 MB
    const size_t actSlice = (size_t)CAP * H_ * 2;       // 21 MB
    const size_t w13Slice = (size_t)2 * H_ * D_ * 2;    // 12.6 MB
    const size_t w2Slice  = (size_t)D_ * H_ * 2;        // 3.1 MB
    const size_t ctrl     = (size_t)NK * 4 * 3 + (size_t)E_ * CAP * 4 + 256;

    char* ws = (char*)d_ws;
    size_t off = 0;
    int*   routerEx  = (int*)(ws + off);   off += (size_t)NK * 4;
    float* routerW   = (float*)(ws + off); off += (size_t)NK * 4;
    int*   tokenSlot = (int*)(ws + off);   off += (size_t)NK * 4;
    int*   slotToken = (int*)(ws + off);   off += (size_t)E_ * CAP * 4;
    int*   cnt       = (int*)(ws + off);   off += 256;

    const size_t bigNeed = ctrl + E_ * (zSlice + actSlice + w13Slice + w2Slice) + E_ * zSlice /*delta*/;
    bool batched = ws_size >= bigNeed;

    router_kernel<<<N_TOK / 4, 256, 0, stream>>>(x, gate_w, routerEx, routerW);
    dispatch_kernel<<<1, 256, 0, stream>>>(routerEx, tokenSlot, slotToken, cnt);

    if (batched) {
        u16* zBuf     = (u16*)(ws + off); off += E_ * zSlice;
        u16* actBuf   = (u16*)(ws + off); off += E_ * actSlice;
        u16* deltaBuf = (u16*)(ws + off); off += E_ * zSlice;
        u16* w13bf    = (u16*)(ws + off); off += E_ * w13Slice;
        u16* w2bf     = (u16*)(ws + off); off += E_ * w2Slice;

        int n13 = E_ * 2 * H_ * D_ / 4, n2 = E_ * D_ * H_ / 4;
        conv_bf16_kernel<<<(n13 + 255) / 256, 256, 0, stream>>>(w13, w13bf, n13);
        conv_bf16_kernel<<<(n2 + 255) / 256, 256, 0, stream>>>(w2, w2bf, n2);
        gather_norm_kernel<<<dim3(CAP / 4, 1, E_), 256, 0, stream>>>(
            x, norm_w, slotToken, cnt, zBuf, zSlice / 2, 0);
        gemm1_kernel<<<dim3(16, CAP / 256, E_), 512, 0, stream>>>(
            zBuf, zSlice / 2, w13bf, w13Slice / 2, actBuf, actSlice / 2, cnt, 0);
        gemm2_kernel<true><<<dim3(3, CAP / 256, E_), 512, 0, stream>>>(
            actBuf, actSlice / 2, w2bf, w2Slice / 2, slotToken, routerW,
            out, deltaBuf, zSlice / 2, cnt, 0);
        combine_kernel<<<(N_TOK * (D_ / 4)) / 256, 256, 0, stream>>>(
            x, deltaBuf, tokenSlot, routerW, out);
    } else {
        u16* zE   = (u16*)(ws + off); off += zSlice;
        u16* actE = (u16*)(ws + off); off += actSlice;
        u16* w13e = (u16*)(ws + off); off += w13Slice;
        u16* w2e  = (u16*)(ws + off); off += w2Slice;

        init_out_kernel<<<(N_TOK * (D_ / 8)) / 256, 256, 0, stream>>>(x, tokenSlot, routerW, out);
        int n13 = 2 * H_ * D_ / 4, n2 = D_ * H_ / 4;
        for (int e = 0; e < E_; ++e) {
            conv_bf16_kernel<<<(n13 + 255) / 256, 256, 0, stream>>>(
                w13 + (size_t)e * 2 * H_ * D_, w13e, n13);
            conv_bf16_kernel<<<(n2 + 255) / 256, 256, 0, stream>>>(
                w2 + (size_t)e * D_ * H_, w2e, n2);
            gather_norm_kernel<<<dim3(CAP / 4, 1, 1), 256, 0, stream>>>(
                x, norm_w, slotToken, cnt, zE, 0, e);
            gemm1_kernel<<<dim3(16, CAP / 256, 1), 512, 0, stream>>>(
                zE, 0, w13e, 0, actE, 0, cnt, e);
            gemm2_kernel<false><<<dim3(3, CAP / 256, 1), 512, 0, stream>>>(
                actE, 0, w2e, 0, slotToken, routerW, out, (u16*)nullptr, 0, cnt, e);
        }
    }
}